// Round 2
// baseline (1366.797 us; speedup 1.0000x reference)
//
#include <hip/hip_runtime.h>
#include <stdint.h>

typedef __attribute__((ext_vector_type(8))) short bf16x8;
typedef __attribute__((ext_vector_type(4))) float f32x4;

#define NROWS 131072
#define HID   512
#define LAT   128
#define NCOL  768
#define BM    64

static __device__ __forceinline__ short f2bf(float f) {
    union { float f; uint32_t u; } v; v.f = f;
    uint32_t r = v.u + 0x7FFFu + ((v.u >> 16) & 1u);
    return (short)(r >> 16);
}

// ---------------------------------------------------------------------------
// prep: weights -> fragment-ready bf16 (B operand of mfma_f32_16x16x32_bf16),
// biases -> fp32[768], zero the output scalar.
// Chunk index ((n*16 + ks)*64 + l), 16B per lane l:
//   element j of lane l = W[k = ks*32 + (l>>4)*8 + j][col = n*16 + (l&15)]
// col order: [0,128) mu | [128,640) u | [640,768) d
// ---------------------------------------------------------------------------
__global__ void prep_kernel(const float* __restrict__ Wmu, const float* __restrict__ bmu,
                            const float* __restrict__ Wu,  const float* __restrict__ bu,
                            const float* __restrict__ Wd,  const float* __restrict__ bd,
                            short* __restrict__ Bfrag, float* __restrict__ bias,
                            float* __restrict__ out) {
    int t = blockIdx.x * blockDim.x + threadIdx.x;
    const int NFRAG = 48 * 16 * 64;
    if (t < NFRAG) {
        int l  = t & 63;
        int ks = (t >> 6) & 15;
        int n  = t >> 10;
        int col = n * 16 + (l & 15);
        int k0  = ks * 32 + (l >> 4) * 8;
        const float* src; int sc, ld;
        if (col < LAT)          { src = Wmu; sc = col;           ld = LAT;     }
        else if (col < LAT * 5) { src = Wu;  sc = col - LAT;     ld = LAT * 4; }
        else                    { src = Wd;  sc = col - LAT * 5; ld = LAT;     }
        bf16x8 v;
        #pragma unroll
        for (int j = 0; j < 8; ++j) v[j] = f2bf(src[(size_t)(k0 + j) * ld + sc]);
        ((bf16x8*)Bfrag)[t] = v;
    } else if (t < NFRAG + NCOL) {
        int col = t - NFRAG;
        float b;
        if (col < LAT)          b = bmu[col];
        else if (col < LAT * 5) b = bu[col - LAT];
        else                    b = bd[col - LAT * 5];
        bias[col] = b;
    } else if (t == NFRAG + NCOL) {
        *out = 0.0f;
    }
}

// ---------------------------------------------------------------------------
// fused: 64-row block, all 768 cols, K=512. 8 waves, wave w -> cols [96w,96w+96).
// A staged bf16 in LDS (double-buffered 64-k chunks, reg-staged, prefetch
// distance 2). Epilogue: Abuf/Epi LDS overlay, 4 passes of 16 rows.
// ---------------------------------------------------------------------------
__launch_bounds__(512, 4)
__global__ void fused_kernel(const float* __restrict__ x, const short* __restrict__ Bfrag,
                             const float* __restrict__ bias, float* __restrict__ out) {
    __shared__ __align__(16) union {
        short Abuf[2][4096];     // 2 x 8 KB: 64 rows x 64 k bf16 (main loop)
        float Epi[16 * 772];     // 16 rows x (768 + 4 pad)       (epilogue)
    } S;
    __shared__ float bsum;

    const int tid  = threadIdx.x;
    const int l    = tid & 63;
    const int w    = tid >> 6;
    const int row0 = blockIdx.x * BM;

    // staging role: wave w stages row-tile (w&3), k-half (w>>2) of each 64-k chunk
    const int srt  = w & 3;
    const int sks  = w >> 2;
    const int srow = srt * 16 + (l & 15);
    const int skk  = sks * 32 + (l >> 4) * 8;
    const int awr  = ((sks * 4 + srt) * 64 + l) * 8;    // shorts

    const float*  xrow = x + (size_t)(row0 + srow) * HID + skk;
    const bf16x8* bwp  = (const bf16x8*)Bfrag + (size_t)w * 6 * 16 * 64 + l;

    f32x4 acc[4][6];
    #pragma unroll
    for (int rt = 0; rt < 4; ++rt)
        #pragma unroll
        for (int i = 0; i < 6; ++i) acc[rt][i] = (f32x4){0.f, 0.f, 0.f, 0.f};

    bf16x8 b0[6], b1[6];
    #pragma unroll
    for (int i = 0; i < 6; ++i) b0[i] = bwp[(size_t)i * 16 * 64];   // ks = 0

    // stage chunk 0 into buf 0 (direct)
    {
        f32x4 q0 = *(const f32x4*)(xrow);
        f32x4 q1 = *(const f32x4*)(xrow + 4);
        bf16x8 av;
        av[0]=f2bf(q0[0]); av[1]=f2bf(q0[1]); av[2]=f2bf(q0[2]); av[3]=f2bf(q0[3]);
        av[4]=f2bf(q1[0]); av[5]=f2bf(q1[1]); av[6]=f2bf(q1[2]); av[7]=f2bf(q1[3]);
        *(bf16x8*)&S.Abuf[0][awr] = av;
    }
    // issue chunk 1 loads (slot parity: chunk m -> px[m&1])
    f32x4 px[2][2];
    px[1][0] = *(const f32x4*)(xrow + 64);
    px[1][1] = *(const f32x4*)(xrow + 64 + 4);
    if (tid == 0) bsum = 0.0f;
    __syncthreads();

    #pragma unroll
    for (int c = 0; c < 8; ++c) {
        const int buf = c & 1;
        #pragma unroll
        for (int i = 0; i < 6; ++i) b1[i] = bwp[((size_t)i * 16 + (2 * c + 1)) * 64];
        if (c <= 5) {   // issue chunk c+2 loads into slot (c&1)
            const float* xq = xrow + (c + 2) * 64;
            px[c & 1][0] = *(const f32x4*)(xq);
            px[c & 1][1] = *(const f32x4*)(xq + 4);
        }
        #pragma unroll
        for (int rt = 0; rt < 4; ++rt) {
            bf16x8 av = *(const bf16x8*)&S.Abuf[buf][(rt * 64 + l) * 8];
            #pragma unroll
            for (int i = 0; i < 6; ++i)
                acc[rt][i] = __builtin_amdgcn_mfma_f32_16x16x32_bf16(av, b0[i], acc[rt][i], 0, 0, 0);
        }
        if (c < 7) {
            #pragma unroll
            for (int i = 0; i < 6; ++i) b0[i] = bwp[((size_t)i * 16 + (2 * c + 2)) * 64];
        }
        #pragma unroll
        for (int rt = 0; rt < 4; ++rt) {
            bf16x8 av = *(const bf16x8*)&S.Abuf[buf][((4 + rt) * 64 + l) * 8];
            #pragma unroll
            for (int i = 0; i < 6; ++i)
                acc[rt][i] = __builtin_amdgcn_mfma_f32_16x16x32_bf16(av, b1[i], acc[rt][i], 0, 0, 0);
        }
        if (c < 7) {    // write-late: convert chunk c+1 (slot (c+1)&1), then barrier
            const f32x4 q0 = px[(c + 1) & 1][0];
            const f32x4 q1 = px[(c + 1) & 1][1];
            bf16x8 av;
            av[0]=f2bf(q0[0]); av[1]=f2bf(q0[1]); av[2]=f2bf(q0[2]); av[3]=f2bf(q0[3]);
            av[4]=f2bf(q1[0]); av[5]=f2bf(q1[1]); av[6]=f2bf(q1[2]); av[7]=f2bf(q1[3]);
            *(bf16x8*)&S.Abuf[buf ^ 1][awr] = av;
            __syncthreads();
        }
    }

    // ------------------------- epilogue (Abuf/Epi overlay) -------------------------
    float pre_bias[6];
    #pragma unroll
    for (int i = 0; i < 6; ++i) pre_bias[i] = bias[(w * 6 + i) * 16 + (l & 15)];

    float my_kl = 0.0f;
    const int r16 = tid >> 5;    // local row within pass, 0..15
    const int jj  = tid & 31;    // latent-stride lane

    #pragma unroll
    for (int pass = 0; pass < 4; ++pass) {
        __syncthreads();         // pass 0: main-loop Abuf reads done; else: prev reads done
        // dump frag rt = pass (16 rows), fp32 + bias
        {
            const int rbase = (l >> 4) * 4;
            #pragma unroll
            for (int i = 0; i < 6; ++i) {
                const int col = (w * 6 + i) * 16 + (l & 15);
                #pragma unroll
                for (int j = 0; j < 4; ++j)
                    S.Epi[(rbase + j) * 772 + col] = acc[pass][i][j] + pre_bias[i];
            }
        }
        __syncthreads();

        const float* rowp = &S.Epi[r16 * 772];
        float s_mu2=0.f, s_u2=0.f, s_d=0.f, s_td=0.f;
        float m00=0.f,m01=0.f,m02=0.f,m03=0.f,m11=0.f,m12=0.f,m13=0.f,m22=0.f,m23=0.f,m33=0.f;
        #pragma unroll
        for (int t4 = 0; t4 < 4; ++t4) {
            const int a = jj + 32 * t4;               // latent index, stride 32 (bank-free)
            float mu = rowp[a];
            float td = rowp[640 + a];
            f32x4 u4 = *(const f32x4*)&rowp[128 + 4 * a];
            s_mu2 += mu * mu;
            s_td  += td;
            float ed  = __expf(td);
            float eid = __expf(-td);
            s_d  += ed;
            s_u2 += u4[0]*u4[0] + u4[1]*u4[1] + u4[2]*u4[2] + u4[3]*u4[3];
            m00 += u4[0]*u4[0]*eid; m01 += u4[0]*u4[1]*eid;
            m02 += u4[0]*u4[2]*eid; m03 += u4[0]*u4[3]*eid;
            m11 += u4[1]*u4[1]*eid; m12 += u4[1]*u4[2]*eid;
            m13 += u4[1]*u4[3]*eid; m22 += u4[2]*u4[2]*eid;
            m23 += u4[2]*u4[3]*eid; m33 += u4[3]*u4[3]*eid;
        }
        #define XRED(v) { v += __shfl_xor(v,1); v += __shfl_xor(v,2); v += __shfl_xor(v,4); \
                          v += __shfl_xor(v,8); v += __shfl_xor(v,16); }
        XRED(s_mu2) XRED(s_u2) XRED(s_d) XRED(s_td)
        XRED(m00) XRED(m01) XRED(m02) XRED(m03) XRED(m11)
        XRED(m12) XRED(m13) XRED(m22) XRED(m23) XRED(m33)

        if (jj == 0) {
            // logdet(I + MtM) by symmetric Gaussian elimination; pivots >= 1
            float a00=1.f+m00, a01=m01, a02=m02, a03=m03;
            float a11=1.f+m11, a12=m12, a13=m13;
            float a22=1.f+m22, a23=m23, a33=1.f+m33;
            float i00 = 1.f / a00;
            float t01=a01*i00, t02=a02*i00, t03=a03*i00;
            a11 -= t01*a01; a12 -= t01*a02; a13 -= t01*a03;
            a22 -= t02*a02; a23 -= t02*a03;
            a33 -= t03*a03;
            float i11 = 1.f / a11;
            float t12=a12*i11, t13=a13*i11;
            a22 -= t12*a12; a23 -= t12*a13;
            a33 -= t13*a13;
            float t23 = a23 / a22;
            a33 -= t23*a23;
            float logdet = __logf(a00 * a11 * a22 * a33);
            my_kl += s_d + s_u2 + s_mu2 - (float)LAT - s_td - logdet;   // 2*kl
        }
    }

    // jj==0 lanes are l = 0 and 32 in each wave
    my_kl += __shfl_xor(my_kl, 32);
    if (l == 0) atomicAdd(&bsum, my_kl);
    __syncthreads();
    if (tid == 0) atomicAdd(out, bsum * (0.5f / (float)NROWS));
}

extern "C" void kernel_launch(void* const* d_in, const int* in_sizes, int n_in,
                              void* d_out, int out_size, void* d_ws, size_t ws_size,
                              hipStream_t stream) {
    (void)in_sizes; (void)n_in; (void)out_size;
    const float* x   = (const float*)d_in[0];
    const float* Wmu = (const float*)d_in[1];
    const float* bmu = (const float*)d_in[2];
    const float* Wu  = (const float*)d_in[3];
    const float* bu  = (const float*)d_in[4];
    const float* Wd  = (const float*)d_in[5];
    const float* bd  = (const float*)d_in[6];
    if (ws_size < (size_t)(48 * 16 * 64 * 16 + NCOL * 4)) return;  // never expected

    short* Bfrag = (short*)d_ws;
    float* bias  = (float*)((char*)d_ws + 48 * 16 * 64 * 16);
    float* out   = (float*)d_out;

    prep_kernel<<<196, 256, 0, stream>>>(Wmu, bmu, Wu, bu, Wd, bd, Bfrag, bias, out);
    fused_kernel<<<NROWS / BM, 512, 0, stream>>>(x, Bfrag, bias, out);
}

// Round 3
// 554.931 us; speedup vs baseline: 2.4630x; 2.4630x over previous
//
#include <hip/hip_runtime.h>
#include <stdint.h>

typedef __attribute__((ext_vector_type(8))) short bf16x8;
typedef __attribute__((ext_vector_type(4))) short bf16x4;
typedef __attribute__((ext_vector_type(4))) float f32x4;

#define NROWS 131072
#define HID   512
#define LAT   128
#define NCOL  768
#define BM    64

static __device__ __forceinline__ short f2bf(float f) {
    union { float f; uint32_t u; } v; v.f = f;
    uint32_t r = v.u + 0x7FFFu + ((v.u >> 16) & 1u);
    return (short)(r >> 16);
}

// ---------------------------------------------------------------------------
// prep: weights -> fragment-ready bf16 (B operand of mfma_f32_16x16x32_bf16),
// biases -> fp32[768], zero the output scalar.
// Chunk index ((n*16 + ks)*64 + l), 16B per lane l:
//   element j of lane l = W[k = ks*32 + (l>>4)*8 + j][col = n*16 + (l&15)]
// col order: [0,128) mu | [128,640) u | [640,768) d
// ---------------------------------------------------------------------------
__global__ void prep_kernel(const float* __restrict__ Wmu, const float* __restrict__ bmu,
                            const float* __restrict__ Wu,  const float* __restrict__ bu,
                            const float* __restrict__ Wd,  const float* __restrict__ bd,
                            short* __restrict__ Bfrag, float* __restrict__ bias,
                            float* __restrict__ out) {
    int t = blockIdx.x * blockDim.x + threadIdx.x;
    const int NFRAG = 48 * 16 * 64;
    if (t < NFRAG) {
        int l  = t & 63;
        int ks = (t >> 6) & 15;
        int n  = t >> 10;
        int col = n * 16 + (l & 15);
        int k0  = ks * 32 + (l >> 4) * 8;
        const float* src; int sc, ld;
        if (col < LAT)          { src = Wmu; sc = col;           ld = LAT;     }
        else if (col < LAT * 5) { src = Wu;  sc = col - LAT;     ld = LAT * 4; }
        else                    { src = Wd;  sc = col - LAT * 5; ld = LAT;     }
        bf16x8 v;
        #pragma unroll
        for (int j = 0; j < 8; ++j) v[j] = f2bf(src[(size_t)(k0 + j) * ld + sc]);
        ((bf16x8*)Bfrag)[t] = v;
    } else if (t < NFRAG + NCOL) {
        int col = t - NFRAG;
        float b;
        if (col < LAT)          b = bmu[col];
        else if (col < LAT * 5) b = bu[col - LAT];
        else                    b = bd[col - LAT * 5];
        bias[col] = b;
    } else if (t == NFRAG + NCOL) {
        *out = 0.0f;
    }
}

// ---------------------------------------------------------------------------
// fused: 64-row block, 1024 threads (16 waves), wave w -> cols [48w,48w+48).
// One block/CU => 4 waves/SIMD structurally; VGPR cap 128 fits (~100 live).
// A staged bf16 in LDS (double-buffered 64-k chunks, reg-staged, distance 2).
// Epilogue: Abuf/Epi overlay, 4 passes x 16 rows, 64 threads/row.
// ---------------------------------------------------------------------------
__launch_bounds__(1024, 1)
__global__ void fused_kernel(const float* __restrict__ x, const short* __restrict__ Bfrag,
                             const float* __restrict__ bias, float* __restrict__ out) {
    __shared__ __align__(16) union {
        short Abuf[2][4096];     // 2 x 8 KB: 64 rows x 64 k bf16 (main loop)
        float Epi[16 * 772];     // 16 rows x (768 + 4 pad)       (epilogue)
    } S;
    __shared__ float bsum;

    const int tid  = threadIdx.x;
    const int l    = tid & 63;
    const int w    = tid >> 6;          // wave 0..15
    const int row0 = blockIdx.x * BM;

    // staging role: thread t stages half of bf16x8 slot idx = t>>1, half h = t&1
    const int idx  = tid >> 1;          // 0..511
    const int h    = tid & 1;
    const int ls   = idx & 63;
    const int srt  = (idx >> 6) & 3;
    const int sks  = idx >> 8;
    const int srow = srt * 16 + (ls & 15);
    const int skk  = sks * 32 + (ls >> 4) * 8 + h * 4;
    const int awr  = idx * 8 + h * 4;   // shorts

    const float*  xrow = x + (size_t)(row0 + srow) * HID + skk;
    const bf16x8* bwp  = (const bf16x8*)Bfrag + (size_t)w * 3 * 16 * 64 + l;

    f32x4 acc[4][3];
    #pragma unroll
    for (int rt = 0; rt < 4; ++rt)
        #pragma unroll
        for (int i = 0; i < 3; ++i) acc[rt][i] = (f32x4){0.f, 0.f, 0.f, 0.f};

    bf16x8 b0[3], b1[3];
    #pragma unroll
    for (int i = 0; i < 3; ++i) b0[i] = bwp[(size_t)i * 16 * 64];   // ks = 0

    // stage chunk 0 into buf 0 (direct)
    {
        f32x4 q = *(const f32x4*)(xrow);
        bf16x4 av;
        av[0]=f2bf(q[0]); av[1]=f2bf(q[1]); av[2]=f2bf(q[2]); av[3]=f2bf(q[3]);
        *(bf16x4*)&S.Abuf[0][awr] = av;
    }
    // issue chunk 1 loads (slot parity: chunk m -> px[m&1])
    f32x4 px[2];
    px[1] = *(const f32x4*)(xrow + 64);
    if (tid == 0) bsum = 0.0f;
    __syncthreads();

    #pragma unroll
    for (int c = 0; c < 8; ++c) {
        const int buf = c & 1;
        #pragma unroll
        for (int i = 0; i < 3; ++i) b1[i] = bwp[((size_t)i * 16 + (2 * c + 1)) * 64];
        if (c <= 5)     // issue chunk c+2 loads into slot (c&1)
            px[c & 1] = *(const f32x4*)(xrow + (c + 2) * 64);
        #pragma unroll
        for (int rt = 0; rt < 4; ++rt) {
            bf16x8 av = *(const bf16x8*)&S.Abuf[buf][(rt * 64 + l) * 8];
            #pragma unroll
            for (int i = 0; i < 3; ++i)
                acc[rt][i] = __builtin_amdgcn_mfma_f32_16x16x32_bf16(av, b0[i], acc[rt][i], 0, 0, 0);
        }
        if (c < 7) {
            #pragma unroll
            for (int i = 0; i < 3; ++i) b0[i] = bwp[((size_t)i * 16 + (2 * c + 2)) * 64];
        }
        #pragma unroll
        for (int rt = 0; rt < 4; ++rt) {
            bf16x8 av = *(const bf16x8*)&S.Abuf[buf][((4 + rt) * 64 + l) * 8];
            #pragma unroll
            for (int i = 0; i < 3; ++i)
                acc[rt][i] = __builtin_amdgcn_mfma_f32_16x16x32_bf16(av, b1[i], acc[rt][i], 0, 0, 0);
        }
        if (c < 7) {    // write-late: convert chunk c+1 (slot (c+1)&1), then barrier
            const f32x4 q = px[(c + 1) & 1];
            bf16x4 av;
            av[0]=f2bf(q[0]); av[1]=f2bf(q[1]); av[2]=f2bf(q[2]); av[3]=f2bf(q[3]);
            *(bf16x4*)&S.Abuf[buf ^ 1][awr] = av;
            __syncthreads();
        }
    }

    // ------------------------- epilogue (Abuf/Epi overlay) -------------------------
    float pre_bias[3];
    #pragma unroll
    for (int i = 0; i < 3; ++i) pre_bias[i] = bias[(w * 3 + i) * 16 + (l & 15)];

    float my_kl = 0.0f;
    const int r16 = w;           // wave w handles Epi row w each pass
    const int jj  = l;           // 64 threads per row

    #pragma unroll
    for (int pass = 0; pass < 4; ++pass) {
        __syncthreads();         // pass 0: Abuf reads done; else: prev pass reads done
        // dump frag rt = pass (block rows pass*16 .. pass*16+15), fp32 + bias
        {
            const int rbase = (l >> 4) * 4;
            #pragma unroll
            for (int i = 0; i < 3; ++i) {
                const int col = (w * 3 + i) * 16 + (l & 15);
                #pragma unroll
                for (int j = 0; j < 4; ++j)
                    S.Epi[(rbase + j) * 772 + col] = acc[pass][i][j] + pre_bias[i];
            }
        }
        __syncthreads();

        const float* rowp = &S.Epi[r16 * 772];
        float s_mu2=0.f, s_u2=0.f, s_d=0.f, s_td=0.f;
        float m00=0.f,m01=0.f,m02=0.f,m03=0.f,m11=0.f,m12=0.f,m13=0.f,m22=0.f,m23=0.f,m33=0.f;
        #pragma unroll
        for (int t2 = 0; t2 < 2; ++t2) {
            const int a = jj + 64 * t2;               // latent index
            float mu = rowp[a];
            float td = rowp[640 + a];
            f32x4 u4 = *(const f32x4*)&rowp[128 + 4 * a];
            s_mu2 += mu * mu;
            s_td  += td;
            float ed  = __expf(td);
            float eid = __expf(-td);
            s_d  += ed;
            s_u2 += u4[0]*u4[0] + u4[1]*u4[1] + u4[2]*u4[2] + u4[3]*u4[3];
            m00 += u4[0]*u4[0]*eid; m01 += u4[0]*u4[1]*eid;
            m02 += u4[0]*u4[2]*eid; m03 += u4[0]*u4[3]*eid;
            m11 += u4[1]*u4[1]*eid; m12 += u4[1]*u4[2]*eid;
            m13 += u4[1]*u4[3]*eid; m22 += u4[2]*u4[2]*eid;
            m23 += u4[2]*u4[3]*eid; m33 += u4[3]*u4[3]*eid;
        }
        #define XRED(v) { v += __shfl_xor(v,1); v += __shfl_xor(v,2); v += __shfl_xor(v,4); \
                          v += __shfl_xor(v,8); v += __shfl_xor(v,16); v += __shfl_xor(v,32); }
        XRED(s_mu2) XRED(s_u2) XRED(s_d) XRED(s_td)
        XRED(m00) XRED(m01) XRED(m02) XRED(m03) XRED(m11)
        XRED(m12) XRED(m13) XRED(m22) XRED(m23) XRED(m33)

        if (jj == 0) {
            // logdet(I + MtM) by symmetric Gaussian elimination; pivots >= 1
            float a00=1.f+m00, a01=m01, a02=m02, a03=m03;
            float a11=1.f+m11, a12=m12, a13=m13;
            float a22=1.f+m22, a23=m23, a33=1.f+m33;
            float i00 = 1.f / a00;
            float t01=a01*i00, t02=a02*i00, t03=a03*i00;
            a11 -= t01*a01; a12 -= t01*a02; a13 -= t01*a03;
            a22 -= t02*a02; a23 -= t02*a03;
            a33 -= t03*a03;
            float i11 = 1.f / a11;
            float t12=a12*i11, t13=a13*i11;
            a22 -= t12*a12; a23 -= t12*a13;
            a33 -= t13*a13;
            float t23 = a23 / a22;
            a33 -= t23*a23;
            float logdet = __logf(a00 * a11 * a22 * a33);
            my_kl += s_d + s_u2 + s_mu2 - (float)LAT - s_td - logdet;   // 2*kl
        }
    }

    if (l == 0) atomicAdd(&bsum, my_kl);   // one lane per wave holds its rows' sum
    __syncthreads();
    if (tid == 0) atomicAdd(out, bsum * (0.5f / (float)NROWS));
}

extern "C" void kernel_launch(void* const* d_in, const int* in_sizes, int n_in,
                              void* d_out, int out_size, void* d_ws, size_t ws_size,
                              hipStream_t stream) {
    (void)in_sizes; (void)n_in; (void)out_size;
    const float* x   = (const float*)d_in[0];
    const float* Wmu = (const float*)d_in[1];
    const float* bmu = (const float*)d_in[2];
    const float* Wu  = (const float*)d_in[3];
    const float* bu  = (const float*)d_in[4];
    const float* Wd  = (const float*)d_in[5];
    const float* bd  = (const float*)d_in[6];
    if (ws_size < (size_t)(48 * 16 * 64 * 16 + NCOL * 4)) return;  // never expected

    short* Bfrag = (short*)d_ws;
    float* bias  = (float*)((char*)d_ws + 48 * 16 * 64 * 16);
    float* out   = (float*)d_out;

    prep_kernel<<<196, 256, 0, stream>>>(Wmu, bmu, Wu, bu, Wd, bd, Bfrag, bias, out);
    fused_kernel<<<NROWS / BM, 1024, 0, stream>>>(x, Bfrag, bias, out);
}

// Round 4
// 478.992 us; speedup vs baseline: 2.8535x; 1.1585x over previous
//
#include <hip/hip_runtime.h>
#include <stdint.h>

typedef __attribute__((ext_vector_type(8)))  short bf16x8;
typedef __attribute__((ext_vector_type(4)))  float f32x4;
typedef __attribute__((ext_vector_type(16))) float f32x16;
typedef __attribute__((ext_vector_type(8)))  unsigned short ushort8;

#define NROWS 131072
#define HID   512
#define LAT   128
#define NCOL  768
#define BM    64
#define EPI_STRIDE 778   // ushorts; 778*2B/4 = 389 words = 5 mod 32 -> 2-way max on row reads

static __device__ __forceinline__ short f2bf(float f) {
    union { float f; uint32_t u; } v; v.f = f;
    uint32_t r = v.u + 0x7FFFu + ((v.u >> 16) & 1u);
    return (short)(r >> 16);
}
static __device__ __forceinline__ float bf2f(unsigned short u) {
    union { uint32_t u; float f; } v; v.u = ((uint32_t)u) << 16;
    return v.f;
}

// ---------------------------------------------------------------------------
// prep: weights -> fragment-ready bf16 (B operand of mfma_f32_32x32x16_bf16),
// biases -> fp32[768], zero output scalar.
// Frag (n in [0,24) colblk, s in [0,32) kstep), lane l: 8 bf16 (16B):
//   elem j = W[k = s*16 + (l>>5)*8 + j][col = n*32 + (l&31)]
// col order: [0,128) mu | [128,640) u | [640,768) d
// ---------------------------------------------------------------------------
__global__ void prep_kernel(const float* __restrict__ Wmu, const float* __restrict__ bmu,
                            const float* __restrict__ Wu,  const float* __restrict__ bu,
                            const float* __restrict__ Wd,  const float* __restrict__ bd,
                            short* __restrict__ Bfrag, float* __restrict__ bias,
                            float* __restrict__ out) {
    int t = blockIdx.x * blockDim.x + threadIdx.x;
    const int NFRAG = 24 * 32 * 64;
    if (t < NFRAG) {
        int l  = t & 63;
        int s  = (t >> 6) & 31;
        int n  = t >> 11;
        int col = n * 32 + (l & 31);
        int k0  = s * 16 + (l >> 5) * 8;
        const float* src; int sc, ld;
        if (col < LAT)          { src = Wmu; sc = col;           ld = LAT;     }
        else if (col < LAT * 5) { src = Wu;  sc = col - LAT;     ld = LAT * 4; }
        else                    { src = Wd;  sc = col - LAT * 5; ld = LAT;     }
        bf16x8 v;
        #pragma unroll
        for (int j = 0; j < 8; ++j) v[j] = f2bf(src[(size_t)(k0 + j) * ld + sc]);
        ((bf16x8*)Bfrag)[t] = v;
    } else if (t < NFRAG + NCOL) {
        int col = t - NFRAG;
        float b;
        if (col < LAT)          b = bmu[col];
        else if (col < LAT * 5) b = bu[col - LAT];
        else                    b = bd[col - LAT * 5];
        bias[col] = b;
    } else if (t == NFRAG + NCOL) {
        *out = 0.0f;
    }
}

// ---------------------------------------------------------------------------
// fused: 64-row block, 768 threads (12 waves), wave w -> cols [64w, 64w+64).
// 32x32x16 MFMA, wave tile = 2x2 frags, acc = 4 x f32x16 = 64 regs.
// A staged bf16 in LDS (dbuf 64-k chunks, 512 stager threads, distance-2).
// Epilogue: one pass, bf16 C dump to LDS (64 x 778), 8 lanes/row, XRED depth 3.
// ---------------------------------------------------------------------------
__global__ __launch_bounds__(768)
void fused_kernel(const float* __restrict__ x, const short* __restrict__ Bfrag,
                  const float* __restrict__ bias, float* __restrict__ out) {
    __shared__ __align__(16) union {
        short A[2][4096];                         // 2 x 8 KB (main loop)
        unsigned short Epi[64 * EPI_STRIDE];      // ~99.6 KB (epilogue)
    } S;
    __shared__ float bsum;

    const int tid  = threadIdx.x;
    const int l    = tid & 63;
    const int w    = tid >> 6;          // 0..11
    const int row0 = blockIdx.x * BM;

    // B frag pointer: wave w owns colblks {2w, 2w+1}; frag (cf,s) at bw[cf*2048 + s*64]
    const bf16x8* bw = (const bf16x8*)Bfrag + (size_t)(2 * w) * 32 * 64 + l;

    f32x16 acc[2][2];
    #pragma unroll
    for (int rf = 0; rf < 2; ++rf)
        #pragma unroll
        for (int cf = 0; cf < 2; ++cf)
            #pragma unroll
            for (int e = 0; e < 16; ++e) acc[rf][cf][e] = 0.0f;

    // staging: threads 0..511, thread t produces LDS slot t (one bf16x8 per chunk)
    // slot t = (s*2 + rt)*64 + lane: row = rt*32 + (lane&31), k = s*16 + (lane>>5)*8
    const bool stager = tid < 512;
    const int  s_   = (tid >> 7) & 3;
    const int  rt_  = (tid >> 6) & 1;
    const int  ls   = tid & 63;
    const int  srow = rt_ * 32 + (ls & 31);
    const int  sk0  = s_ * 16 + (ls >> 5) * 8;
    const float* xptr = x + (size_t)(row0 + srow) * HID + sk0;
    const int  awr  = tid * 8;          // shorts

    bf16x8 bA[2], bB[2];
    bA[0] = bw[0];
    bA[1] = bw[2048];

    f32x4 px[2][2];
    if (stager) {
        f32x4 q0 = *(const f32x4*)(xptr);
        f32x4 q1 = *(const f32x4*)(xptr + 4);
        bf16x8 av;
        av[0]=f2bf(q0[0]); av[1]=f2bf(q0[1]); av[2]=f2bf(q0[2]); av[3]=f2bf(q0[3]);
        av[4]=f2bf(q1[0]); av[5]=f2bf(q1[1]); av[6]=f2bf(q1[2]); av[7]=f2bf(q1[3]);
        *(bf16x8*)&S.A[0][awr] = av;
        px[1][0] = *(const f32x4*)(xptr + 64);      // chunk 1 -> slot 1
        px[1][1] = *(const f32x4*)(xptr + 68);
    }
    if (tid == 0) bsum = 0.0f;
    __syncthreads();

#define KSTEP(SB, CUR, NXT, NIDX, DONEXT) do {                                          \
        if (DONEXT) { NXT[0] = bw[(size_t)(NIDX) * 64];                                  \
                      NXT[1] = bw[(size_t)(2048 + (NIDX) * 64)]; }                       \
        bf16x8 a0 = *(const bf16x8*)&S.A[buf][(((SB) * 2 + 0) * 64 + l) * 8];            \
        bf16x8 a1 = *(const bf16x8*)&S.A[buf][(((SB) * 2 + 1) * 64 + l) * 8];            \
        acc[0][0] = __builtin_amdgcn_mfma_f32_32x32x16_bf16(a0, CUR[0], acc[0][0], 0,0,0);\
        acc[0][1] = __builtin_amdgcn_mfma_f32_32x32x16_bf16(a0, CUR[1], acc[0][1], 0,0,0);\
        acc[1][0] = __builtin_amdgcn_mfma_f32_32x32x16_bf16(a1, CUR[0], acc[1][0], 0,0,0);\
        acc[1][1] = __builtin_amdgcn_mfma_f32_32x32x16_bf16(a1, CUR[1], acc[1][1], 0,0,0);\
    } while (0)

    #pragma unroll
    for (int c = 0; c < 8; ++c) {
        const int buf = c & 1;
        if (stager && c <= 5) {             // issue chunk c+2 -> slot (c&1)
            px[c & 1][0] = *(const f32x4*)(xptr + (c + 2) * 64);
            px[c & 1][1] = *(const f32x4*)(xptr + (c + 2) * 64 + 4);
        }
        KSTEP(0, bA, bB, c * 4 + 1, true);
        KSTEP(1, bB, bA, c * 4 + 2, true);
        KSTEP(2, bA, bB, c * 4 + 3, true);
        KSTEP(3, bB, bA, (c + 1) * 4, c < 7);
        if (c < 7) {
            if (stager) {                   // write chunk c+1 from slot (c+1)&1
                const f32x4 q0 = px[(c + 1) & 1][0];
                const f32x4 q1 = px[(c + 1) & 1][1];
                bf16x8 av;
                av[0]=f2bf(q0[0]); av[1]=f2bf(q0[1]); av[2]=f2bf(q0[2]); av[3]=f2bf(q0[3]);
                av[4]=f2bf(q1[0]); av[5]=f2bf(q1[1]); av[6]=f2bf(q1[2]); av[7]=f2bf(q1[3]);
                *(bf16x8*)&S.A[buf ^ 1][awr] = av;
            }
            __syncthreads();
        }
    }
#undef KSTEP

    // ------------------------- epilogue -------------------------
    __syncthreads();                        // all A-reads done; overlay Epi
    float pre_bias[2];
    pre_bias[0] = bias[w * 64 + (l & 31)];
    pre_bias[1] = bias[w * 64 + 32 + (l & 31)];

    // C layout (m74/m101): col = lane&31, row = (r&3) + 8*(r>>2) + 4*(lane>>5)
    #pragma unroll
    for (int rf = 0; rf < 2; ++rf)
        #pragma unroll
        for (int cf = 0; cf < 2; ++cf) {
            const int colg = w * 64 + cf * 32 + (l & 31);
            const int rb   = rf * 32 + 4 * (l >> 5);
            #pragma unroll
            for (int r = 0; r < 16; ++r) {
                const int row = rb + (r & 3) + 8 * (r >> 2);
                S.Epi[row * EPI_STRIDE + colg] =
                    (unsigned short)f2bf(acc[rf][cf][r] + pre_bias[cf]);
            }
        }
    __syncthreads();

    float my_kl = 0.0f;
    if (tid < 512) {                        // 8 lanes per row, rows 0..63
        const int rr = tid >> 3;
        const int j  = tid & 7;
        const unsigned short* rowp = &S.Epi[rr * EPI_STRIDE];
        float s_mu2=0.f, s_u2=0.f, s_d=0.f, s_td=0.f;
        float m00=0.f,m01=0.f,m02=0.f,m03=0.f,m11=0.f,m12=0.f,m13=0.f,m22=0.f,m23=0.f,m33=0.f;

#define LACC(MU, TD, UV, B) do {                                            \
        float mu = bf2f(MU); float td = bf2f(TD);                           \
        float u0 = bf2f(UV[(B)+0]), u1 = bf2f(UV[(B)+1]);                   \
        float u2 = bf2f(UV[(B)+2]), u3 = bf2f(UV[(B)+3]);                   \
        s_mu2 += mu * mu; s_td += td;                                       \
        float ed = __expf(td), eid = __expf(-td);                           \
        s_d += ed;                                                          \
        s_u2 += u0*u0 + u1*u1 + u2*u2 + u3*u3;                              \
        m00 += u0*u0*eid; m01 += u0*u1*eid; m02 += u0*u2*eid; m03 += u0*u3*eid; \
        m11 += u1*u1*eid; m12 += u1*u2*eid; m13 += u1*u3*eid;               \
        m22 += u2*u2*eid; m23 += u2*u3*eid; m33 += u3*u3*eid;               \
    } while (0)

        #pragma unroll
        for (int q = 0; q < 2; ++q) {
            const int a0 = j * 16 + q * 8;      // 8 latents, contiguous
            ushort8 muv = *(const ushort8*)&rowp[a0];
            ushort8 tdv = *(const ushort8*)&rowp[640 + a0];
            ushort8 uv0 = *(const ushort8*)&rowp[128 + 4 * a0];
            ushort8 uv1 = *(const ushort8*)&rowp[128 + 4 * a0 + 8];
            ushort8 uv2 = *(const ushort8*)&rowp[128 + 4 * a0 + 16];
            ushort8 uv3 = *(const ushort8*)&rowp[128 + 4 * a0 + 24];
            LACC(muv[0], tdv[0], uv0, 0); LACC(muv[1], tdv[1], uv0, 4);
            LACC(muv[2], tdv[2], uv1, 0); LACC(muv[3], tdv[3], uv1, 4);
            LACC(muv[4], tdv[4], uv2, 0); LACC(muv[5], tdv[5], uv2, 4);
            LACC(muv[6], tdv[6], uv3, 0); LACC(muv[7], tdv[7], uv3, 4);
        }
#undef LACC

#define XRED3(v) { v += __shfl_xor(v,1); v += __shfl_xor(v,2); v += __shfl_xor(v,4); }
        XRED3(s_mu2) XRED3(s_u2) XRED3(s_d) XRED3(s_td)
        XRED3(m00) XRED3(m01) XRED3(m02) XRED3(m03) XRED3(m11)
        XRED3(m12) XRED3(m13) XRED3(m22) XRED3(m23) XRED3(m33)
#undef XRED3

        if (j == 0) {
            // logdet(I + MtM) via symmetric Gaussian elimination; pivots >= 1
            float a00=1.f+m00, a01=m01, a02=m02, a03=m03;
            float a11=1.f+m11, a12=m12, a13=m13;
            float a22=1.f+m22, a23=m23, a33=1.f+m33;
            float i00 = 1.f / a00;
            float t01=a01*i00, t02=a02*i00, t03=a03*i00;
            a11 -= t01*a01; a12 -= t01*a02; a13 -= t01*a03;
            a22 -= t02*a02; a23 -= t02*a03;
            a33 -= t03*a03;
            float i11 = 1.f / a11;
            float t12=a12*i11, t13=a13*i11;
            a22 -= t12*a12; a23 -= t12*a13;
            a33 -= t13*a13;
            float t23 = a23 / a22;
            a33 -= t23*a23;
            float logdet = __logf(a00 * a11 * a22 * a33);
            my_kl = s_d + s_u2 + s_mu2 - (float)LAT - s_td - logdet;   // 2*kl
        }
        // combine the 8 row-leaders (l = 0,8,..,56) of each wave
        my_kl += __shfl_xor(my_kl, 8);
        my_kl += __shfl_xor(my_kl, 16);
        my_kl += __shfl_xor(my_kl, 32);
        if (l == 0) atomicAdd(&bsum, my_kl);
    }
    __syncthreads();
    if (tid == 0) atomicAdd(out, bsum * (0.5f / (float)NROWS));
}

extern "C" void kernel_launch(void* const* d_in, const int* in_sizes, int n_in,
                              void* d_out, int out_size, void* d_ws, size_t ws_size,
                              hipStream_t stream) {
    (void)in_sizes; (void)n_in; (void)out_size;
    const float* x   = (const float*)d_in[0];
    const float* Wmu = (const float*)d_in[1];
    const float* bmu = (const float*)d_in[2];
    const float* Wu  = (const float*)d_in[3];
    const float* bu  = (const float*)d_in[4];
    const float* Wd  = (const float*)d_in[5];
    const float* bd  = (const float*)d_in[6];
    if (ws_size < (size_t)(24 * 32 * 64 * 16 + NCOL * 4)) return;  // never expected

    short* Bfrag = (short*)d_ws;
    float* bias  = (float*)((char*)d_ws + 24 * 32 * 64 * 16);
    float* out   = (float*)d_out;

    prep_kernel<<<196, 256, 0, stream>>>(Wmu, bmu, Wu, bu, Wd, bd, Bfrag, bias, out);
    fused_kernel<<<NROWS / BM, 768, 0, stream>>>(x, Bfrag, bias, out);
}